// Round 14
// baseline (309.794 us; speedup 1.0000x reference)
//
#include <hip/hip_runtime.h>
#include <math.h>

#define B_   16
#define C_   32
#define N_   2048
#define K_   24
#define BNK_ (B_*N_*K_)      /* 786432 */

typedef float vf2 __attribute__((ext_vector_type(2)));
typedef __attribute__((ext_vector_type(8))) short bf16x8;   /* 8 bf16 = 4 VGPRs */
typedef __attribute__((ext_vector_type(4))) float f32x4;

/* ws layout (float/int32 units), ~51 MB total (12,747,008 f) */
#define WS_XT   0u           /* xt[b][n][c]  : 1048576 f            */
#define WS_XXD  1048576u     /* xx fp64      : 65536 f              */
#define WS_XXF  1114112u     /* -xx/2 fp32   : 32768 f              */
#define WS_IDX  1146880u     /* idx[b][n][k] : 786432 i             */
#define WS_D2   1933312u     /* d2 [b][n][k] : 786432 f             */
#define WS_ATT  2719744u     /* att[b][n][k] : 786432 f             */
#define WS_LOG  3506176u     /* logitsT[k][bn]: 786432 f            */
#define WS_ST   4292608u     /* sum/sumsq    : 128 f                */
#define WS_AB   4292736u     /* BN A,B       : 128 f  (unused now)  */
#define WS_W    4292864u     /* W[m]  att-hist : 32768 f            */
#define WS_W2   4325632u     /* W2[m] att2-hist: 32768 f            */
#define WS_Y    4358400u     /* Y[m][256]: base|attn|upd|res : 8388608 f */
#define WS_L    4358400u     /* k1 lists 512*16*12*64 = 6291456 f
                                (aliases Y; dead before kY)         */
#define WS_HL   10649856u    /* bf16 hi/lo split [b*2048][16u32 hi|16u32 lo]
                                = 1048576 f; aliases Y tail; dead before kY */

__device__ __forceinline__ unsigned short bf16rne(float f) {
  unsigned int u = __float_as_uint(f);
  return (unsigned short)((u + 0x7FFFu + ((u >> 16) & 1u)) >> 16);
}

/* VALU-pipe cross-lane add via DPP (no DS ops). Masked lanes add 0. */
#define DPP_ADD(p, ctrl, rm)                                                  \
  (p) += __int_as_float(__builtin_amdgcn_update_dpp(                          \
      0, __float_as_int(p), (ctrl), (rm), 0xf, true))

/* ---------------- K0: transpose x -> xt, norms, bf16 hi/lo split ---------- */
__global__ __launch_bounds__(256) void k0_prep(const float* __restrict__ x,
                                               float* __restrict__ ws) {
  const int i = blockIdx.x;                 /* 128 blocks */
  const int xcd = i & 7, j = i >> 3;
  const int b = 2 * xcd + (j & 1);
  const int half = j >> 1;                  /* 0..7 */
  const int t = (b << 11) + (half << 8) + threadIdx.x;
  const int n = t & 2047;
  const float* xp = x + ((size_t)b * C_ * N_) + n;
  float4* xt4 = (float4*)(ws + WS_XT + (size_t)t * C_);
  uint4*  hl  = (uint4*)(ws + WS_HL) + (size_t)t * 8;
  unsigned int hu[16], lu[16];
  double s = 0.0;
#pragma unroll
  for (int cg = 0; cg < 8; ++cg) {
    float4 v;
    v.x = xp[(size_t)(4*cg  ) * N_];
    v.y = xp[(size_t)(4*cg+1) * N_];
    v.z = xp[(size_t)(4*cg+2) * N_];
    v.w = xp[(size_t)(4*cg+3) * N_];
    xt4[cg] = v;
    s = fma((double)v.x, (double)v.x, s);
    s = fma((double)v.y, (double)v.y, s);
    s = fma((double)v.z, (double)v.z, s);
    s = fma((double)v.w, (double)v.w, s);
    unsigned short h0 = bf16rne(v.x), h1 = bf16rne(v.y);
    unsigned short h2 = bf16rne(v.z), h3 = bf16rne(v.w);
    float l0 = v.x - __uint_as_float((unsigned int)h0 << 16);
    float l1 = v.y - __uint_as_float((unsigned int)h1 << 16);
    float l2 = v.z - __uint_as_float((unsigned int)h2 << 16);
    float l3 = v.w - __uint_as_float((unsigned int)h3 << 16);
    hu[2*cg]   = (unsigned int)h0 | ((unsigned int)h1 << 16);
    hu[2*cg+1] = (unsigned int)h2 | ((unsigned int)h3 << 16);
    lu[2*cg]   = (unsigned int)bf16rne(l0) | ((unsigned int)bf16rne(l1) << 16);
    lu[2*cg+1] = (unsigned int)bf16rne(l2) | ((unsigned int)bf16rne(l3) << 16);
  }
#pragma unroll
  for (int q = 0; q < 4; ++q) {
    uint4 hv; hv.x = hu[4*q]; hv.y = hu[4*q+1]; hv.z = hu[4*q+2]; hv.w = hu[4*q+3];
    hl[q] = hv;
    uint4 lv; lv.x = lu[4*q]; lv.y = lu[4*q+1]; lv.z = lu[4*q+2]; lv.w = lu[4*q+3];
    hl[4+q] = lv;
  }
  ((double*)(ws + WS_XXD))[t] = s;
  ws[WS_XXF + t] = -0.5f * (float)s;        /* NEGATED half-norm: acc init */
  ws[WS_W + t] = 0.f;
  ws[WS_W2 + t] = 0.f;
  if (t < 128) ws[WS_ST + t] = 0.f;
}

/* ---------------- K1a (MFMA + LDS-staged A-panel, 4 tiles/barrier) --------
   R14: extend R12's winning direction 2->4 tiles per barrier (8 barriers,
   4x compute per vmcnt drain). 16KB LDS -> 9 blocks/CU LDS-limit >= 8
   needed, occupancy preserved at 8 waves/SIMD.                            */
__global__ __launch_bounds__(256, 8) void k1a_mfma(float* __restrict__ ws) {
  __shared__ unsigned short tl[2][4096];    /* 2 x 8KB (4-tile) buffers */
  const int lane = threadIdx.x & 63;
  const int wv   = __builtin_amdgcn_readfirstlane(threadIdx.x >> 6);
  const int i = blockIdx.x;                 /* 2048 blocks */
  const int xcd = i & 7, j = i >> 3;        /* j 0..255 */
  const int b = 2 * xcd + (j & 1);
  const int j2 = j >> 1;                    /* 0..127 */
  const int nblk = j2 >> 2;                 /* 0..31 : 64-point group */
  const int mq   = j2 & 3;                  /* 0..3  : m quarter */
  const int l16 = lane & 15, lg = lane >> 4;

  const unsigned short* HL = (const unsigned short*)(ws + WS_HL) + ((size_t)b << 17);
  const int nrow = (nblk << 6) + (wv << 4) + l16;
  const bf16x8 bh = *(const bf16x8*)(HL + ((size_t)nrow << 6) + (lg << 3));
  const bf16x8 bl = *(const bf16x8*)(HL + ((size_t)nrow << 6) + 32 + (lg << 3));

  const int mbase = mq << 9;                /* 512-m quarter */
  const float4* nxx = (const float4*)(ws + WS_XXF + (b << 11) + mbase);

  /* staging source: lane covers row=lane>>3 (0..7) of a tile, slot=lane&7,
     source slot pre-swizzled so linear LDS dest ends up XOR-swizzled */
  const int srow = lane >> 3;
  const int sslot = (lane & 7) ^ srow;
  const unsigned short* Sp = HL + ((size_t)(mbase + srow) << 6) + (sslot << 3);

  /* reader LDS offsets (ushort units), same XOR involution */
  const int ah_off = (l16 << 6) + (((lg    ) ^ (l16 & 7)) << 3);
  const int al_off = (l16 << 6) + (((4 | lg) ^ (l16 & 7)) << 3);

  /* prologue: wave 0 stages tiles 0..3 into buf 0 */
  if (wv == 0) {
#pragma unroll
    for (int u = 0; u < 8; ++u) {
      const unsigned short* sp = Sp + ((size_t)(u >> 1) << 10) + (u & 1) * 512;
      __builtin_amdgcn_global_load_lds(
          (const __attribute__((address_space(1))) unsigned int*)(const void*)sp,
          (__attribute__((address_space(3))) unsigned int*)(void*)&tl[0][u * 512],
          16, 0, 0);
    }
  }
  __syncthreads();

  float val[12];
#pragma unroll
  for (int j0 = 0; j0 < 12; ++j0) val[j0] = -3.4e38f;
  int id = mbase + (lg << 2);               /* m of reg 0, tile 0 */

#pragma unroll 1
  for (int tt = 0; tt < 8; ++tt) {
    const int cur = tt & 1;
    if (tt < 7 && wv == (tt & 3)) {         /* rotating staging wave */
#pragma unroll
      for (int u = 0; u < 8; ++u) {
        const int tile = 4 * tt + 4 + (u >> 1);
        const unsigned short* sp = Sp + ((size_t)tile << 10) + (u & 1) * 512;
        __builtin_amdgcn_global_load_lds(
            (const __attribute__((address_space(1))) unsigned int*)(const void*)sp,
            (__attribute__((address_space(3))) unsigned int*)(void*)&tl[cur ^ 1][u * 512],
            16, 0, 0);
      }
    }
#pragma unroll
    for (int sub = 0; sub < 4; ++sub) {     /* four tiles from this buffer */
      const int t = 4 * tt + sub;
      const int base = sub << 10;
      bf16x8 ah = *(const bf16x8*)(&tl[cur][base + ah_off]);
      bf16x8 al = *(const bf16x8*)(&tl[cur][base + al_off]);
      float4 xq = nxx[(t << 2) + lg];       /* -xx/2 for this tile's 4 m's */
      f32x4 acc;
      acc[0] = xq.x; acc[1] = xq.y; acc[2] = xq.z; acc[3] = xq.w;
      acc = __builtin_amdgcn_mfma_f32_16x16x32_bf16(ah, bh, acc, 0, 0, 0);
      acc = __builtin_amdgcn_mfma_f32_16x16x32_bf16(al, bh, acc, 0, 0, 0);
      acc = __builtin_amdgcn_mfma_f32_16x16x32_bf16(ah, bl, acc, 0, 0, 0);
#pragma unroll
      for (int r = 0; r < 4; ++r) {
        int sb = (__float_as_int(acc[r]) & ~2047) | (id + r);
        float sp2 = __int_as_float(sb);
#pragma unroll
        for (int j0 = 11; j0 >= 1; --j0)
          val[j0] = __builtin_amdgcn_fmed3f(val[j0 - 1], val[j0], sp2);
        val[0] = fmaxf(val[0], sp2);
      }
      id += 16;
    }
    __syncthreads();                        /* drains vmcnt -> buf^1 ready */
  }
  /* subset slot = mq*4 + lane-group (16 slots); point-in-group = wv*16+l16 */
  const int pg = (b << 5) + nblk;
  float* Lp = ws + WS_L +
      (((size_t)pg * 16 + (mq << 2) + lg) * 12) * 64 + (wv << 4) + l16;
#pragma unroll
  for (int j0 = 0; j0 < 12; ++j0) Lp[(size_t)j0 * 64] = val[j0];
}

/* ---------------- K1b: union select (16x12=192) + exact fp64 re-rank ----- */
__global__ __launch_bounds__(64) void k1b_sel(float* __restrict__ ws) {
  const float* xt = ws + WS_XT;
  const double* xxd = (const double*)(ws + WS_XXD);
  const int lane = threadIdx.x & 63;
  const int i = blockIdx.x;                 /* 512 blocks */
  const int xcd = i & 7, j = i >> 3;        /* j 0..63 */
  const int b = 2 * xcd + (j & 1);
  const int sub = j >> 1;                   /* 0..31 */
  const int pg = (b << 5) + sub;
  const int bn = (b << 11) + (sub << 6) + lane;

  float val[28];
#pragma unroll
  for (int j0 = 0; j0 < 28; ++j0) val[j0] = -3.4e38f;
  const float* Lp = ws + WS_L + ((size_t)pg * 16 * 12) * 64 + lane;
#pragma unroll 4
  for (int t = 0; t < 192; ++t) {
    float sp = Lp[(size_t)t * 64];
#pragma unroll
    for (int j0 = 27; j0 >= 1; --j0)
      val[j0] = __builtin_amdgcn_fmed3f(val[j0 - 1], val[j0], sp);
    val[0] = fmaxf(val[0], sp);
  }

  double xnd[C_];
  {
    const float* p = xt + (size_t)bn * C_;
#pragma unroll
    for (int c = 0; c < C_; ++c) xnd[c] = (double)p[c];
  }
  double dl[K_];
#pragma unroll
  for (int j0 = 0; j0 < K_; ++j0) dl[j0] = -1.7e308;

#pragma unroll 1
  for (int j0 = 0; j0 < 28; ++j0) {
    const int m = __float_as_int(val[j0]) & 2047;
    const float* r = xt + ((size_t)((b << 11) + m)) * C_;
    double a0 = 0.0, a1 = 0.0;
#pragma unroll
    for (int c = 0; c < 16; ++c) {
      a0 = fma((double)r[c],      xnd[c],      a0);
      a1 = fma((double)r[c + 16], xnd[c + 16], a1);
    }
    double s = 2.0 * (a0 + a1) - xxd[(b << 11) + m];
    long long bits = (__double_as_longlong(s) & 0xFFFFFFFFFFFFF800ll) | (long long)m;
    double sp = __longlong_as_double(bits);
    if (sp > dl[K_ - 1]) {     /* guarded insert */
      bool c2 = true;
#pragma unroll
      for (int jj = K_ - 1; jj >= 1; --jj) {
        bool c1 = sp > dl[jj - 1];
        dl[jj] = c1 ? dl[jj - 1] : (c2 ? sp : dl[jj]);
        c2 = c1;
      }
      if (c2) dl[0] = sp;
    }
  }

  int*   op = (int*)ws + WS_IDX + (size_t)bn * K_;
  float* dp = ws + WS_D2 + (size_t)bn * K_;
  const double xxn = xxd[bn];
#pragma unroll
  for (int rr = 0; rr < K_; ++rr) {
    long long bl = __double_as_longlong(dl[rr]);
    op[rr] = (int)(bl & 0x7FFll);
    dp[rr] = (float)(xxn - __longlong_as_double(bl & 0xFFFFFFFFFFFFF800ll));
  }
}

/* ---------------- KY: Y[m] = [xt·w1c^T | xt·w1n^T | xt·updw^T | xt·resw^T] */
__global__ __launch_bounds__(256) void kY(const float* __restrict__ w1,
                                          const float* __restrict__ updw,
                                          const float* __restrict__ resw,
                                          float* __restrict__ ws) {
  const int lane = threadIdx.x & 63;
  const int wv   = __builtin_amdgcn_readfirstlane(threadIdx.x >> 6);
  const int i = blockIdx.x;                 /* 1024 blocks */
  const int xcd = i & 7, j = i >> 3;        /* j 0..127 */
  const int b = 2 * xcd + (j & 1);
  const int j2 = j >> 1;                    /* 0..63 */
  const int slot = (j2 << 2) | wv;          /* 0..255 */
  const int s  = slot & 7;                  /* slice 0..7 (uniform) */
  const int pg = slot >> 3;                 /* 0..31 */
  const int p = (b << 11) + (pg << 6) + lane;
  const float* xt = ws + WS_XT;

  float row[C_];
  {
    const float4* rp = (const float4*)(xt + (size_t)p * C_);
#pragma unroll
    for (int q = 0; q < 8; ++q) {
      float4 v = rp[q];
      row[4*q] = v.x; row[4*q+1] = v.y; row[4*q+2] = v.z; row[4*q+3] = v.w;
    }
  }
  const int part = s >> 1;                  /* 0..3 (uniform) */
  const int hch  = (s & 1) * 32;            /* first channel of slice */
  const float* W   = (part == 0) ? w1 : (part == 1) ? (w1 + 32)
                   : (part == 2) ? updw : resw;          /* uniform */
  const int stride = (part < 2) ? 80 : 32;
  float* yp = ws + WS_Y + (size_t)p * 256 + s * 32;
#pragma unroll 2
  for (int og = 0; og < 8; ++og) {
    float a[4] = {0.f, 0.f, 0.f, 0.f};
#pragma unroll
    for (int u = 0; u < 4; ++u) {
      const float* wr = W + (hch + 4 * og + u) * stride; /* uniform -> s_load */
#pragma unroll
      for (int c = 0; c < C_; ++c) a[u] = fmaf(row[c], wr[c], a[u]);
    }
    float4 st; st.x = a[0]; st.y = a[1]; st.z = a[2]; st.w = a[3];
    ((float4*)yp)[og] = st;
  }
}

/* ---------------- K2L: logits via 16x16x32 split-MFMA ---------------------
   R14: occupancy is VGPR-capped at 4 waves/SIMD (R10/R12 proved 8-wave
   spills) -> hide the rv-gather latency with ILP instead of TLP: per bn,
   load all 8 mk + all 32 rv into regs back-to-back (one latency exposure
   instead of ~8), then run the MFMA section from registers. rbf hi-split
   switched rne->trunc (lo's rne absorbs the error; same 2^-17 accuracy,
   fewer VALU). VGPR est ~108 < 128 cap. Spill-watch on FETCH.             */
__global__ __launch_bounds__(256, 4) void k2_logits(const float* __restrict__ w1,
                                                    const float* __restrict__ w2,
                                                    float* __restrict__ ws) {
  __shared__ unsigned short A_s[4][2048];   /* [wave][32 rows][hi32|lo32] 16KB */
  __shared__ float dist_s[4][24];
  const int lane = threadIdx.x & 63;
  const int wv   = __builtin_amdgcn_readfirstlane(threadIdx.x >> 6);
  const int l16 = lane & 15, lg = lane >> 4;
  const int i = blockIdx.x;                 /* 2048 blocks */
  const int xcd = i & 7, j = i >> 3;        /* j 0..255 */
  const int b = 2 * xcd + (j & 1);
  const int grp = j >> 1;                   /* 0..127 : 16-point group */
  const float* Y = ws + WS_Y;

  /* zero A (rows 24..31 and r>=16 slots stay zero forever) */
  {
    uint4 z; z.x = 0; z.y = 0; z.z = 0; z.w = 0;
    uint4* az = (uint4*)&A_s[wv][0];
    az[lane] = z; az[lane + 64] = z; az[lane + 128] = z; az[lane + 192] = z;
  }

  /* W1 B-fragments (hi/lo x 4 o-tiles): lane = o-col l16, elems r=lg*8..+7 */
  bf16x8 w1h[4], w1l[4];
  float w2r[4];
#pragma unroll
  for (int t = 0; t < 4; ++t) {
    const int o = t * 16 + l16;
    w2r[t] = w2[o];
    bf16x8 vh, vl;
#pragma unroll
    for (int jj = 0; jj < 8; ++jj) {
      const int r = lg * 8 + jj;
      float v = (r < 16) ? w1[o * 80 + 64 + r] : 0.f;
      unsigned short h = bf16rne(v);
      float lo = v - __uint_as_float((unsigned int)h << 16);
      vh[jj] = (short)h;
      vl[jj] = (short)bf16rne(lo);
    }
    w1h[t] = vh; w1l[t] = vl;
  }

#pragma unroll 1
  for (int q = 0; q < 4; ++q) {
    const int bn = (b << 11) + (grp << 4) + (wv << 2) + q;        /* uniform */
    const float* dpp = ws + WS_D2 + (size_t)bn * K_;
    if (lane < K_) dist_s[wv][lane] = sqrtf(fmaxf(dpp[lane], 1e-12f));
    /* rbf -> bf16 hi(trunc)/lo(rne) into A rows: 3 (k,r-pair) items/lane */
#pragma unroll
    for (int t = 0; t < 3; ++t) {
      const int f2 = lane + (t << 6);       /* 0..191 = k*8 + r2 */
      const int k = f2 >> 3, r2 = f2 & 7;
      const float d = dist_s[wv][k];
      float d0 = d - (float)(2 * r2    ) * (5.0f / 15.0f);
      float d1 = d - (float)(2 * r2 + 1) * (5.0f / 15.0f);
      float e0 = fminf(fmaxf(__expf(-10.f * d0 * d0), 1e-10f), 1.0f);
      float e1 = fminf(fmaxf(__expf(-10.f * d1 * d1), 1e-10f), 1.0f);
      unsigned int u0 = __float_as_uint(e0), u1 = __float_as_uint(e1);
      unsigned short h0 = (unsigned short)(u0 >> 16);   /* trunc split */
      unsigned short h1 = (unsigned short)(u1 >> 16);
      float lo0 = e0 - __uint_as_float(u0 & 0xFFFF0000u);
      float lo1 = e1 - __uint_as_float(u1 & 0xFFFF0000u);
      unsigned short g0 = bf16rne(lo0), g1 = bf16rne(lo1);
      const int slot = r2 >> 2;             /* logical hi slot 0..1 */
      const int us = (2 * r2) & 7;          /* even ushort within slot */
      const int ph = (slot     ^ (k & 7));
      const int pl = ((4|slot) ^ (k & 7));
      *(unsigned int*)&A_s[wv][(k << 6) + (ph << 3) + us] =
          (unsigned int)h0 | ((unsigned int)h1 << 16);
      *(unsigned int*)&A_s[wv][(k << 6) + (pl << 3) + us] =
          (unsigned int)g0 | ((unsigned int)g1 << 16);
    }
    /* hoisted: all 8 mk + ba + ALL 32 rv loads issued back-to-back */
    int mk0[4], mk1[4];
#pragma unroll
    for (int reg = 0; reg < 4; ++reg) {
      mk0[reg] = ((const int*)ws)[WS_IDX + (size_t)bn * K_ + ((lg << 2) + reg)] & 2047;
      const int k1i = 16 + (lg << 2) + reg;
      mk1[reg] = ((const int*)ws)[WS_IDX + (size_t)bn * K_ + (k1i < K_ ? k1i : 0)] & 2047;
    }
    float ba[4];
#pragma unroll
    for (int t = 0; t < 4; ++t) ba[t] = Y[(size_t)bn * 256 + t * 16 + l16];
    float rv0[16], rv1[16];
#pragma unroll
    for (int t = 0; t < 4; ++t) {
#pragma unroll
      for (int reg = 0; reg < 4; ++reg) {
        rv0[(t << 2) + reg] =
            Y[(size_t)((b << 11) + mk0[reg]) * 256 + 64 + t * 16 + l16];
        rv1[(t << 2) + reg] =
            Y[(size_t)((b << 11) + mk1[reg]) * 256 + 64 + t * 16 + l16];
      }
    }

#pragma unroll
    for (int kt = 0; kt < 2; ++kt) {
      const int row = kt * 16 + l16;
      bf16x8 ah = *(const bf16x8*)&A_s[wv][(row << 6) + (((lg    ) ^ (row & 7)) << 3)];
      bf16x8 al = *(const bf16x8*)&A_s[wv][(row << 6) + (((4 | lg) ^ (row & 7)) << 3)];
      float sum[4] = {0.f, 0.f, 0.f, 0.f};
#pragma unroll
      for (int t = 0; t < 4; ++t) {
        f32x4 acc;
#pragma unroll
        for (int reg = 0; reg < 4; ++reg) {
          float rv = kt ? rv1[(t << 2) + reg] : rv0[(t << 2) + reg];
          acc[reg] = ba[t] + rv;            /* C init = ba + rv */
        }
        acc = __builtin_amdgcn_mfma_f32_16x16x32_bf16(ah, w1h[t], acc, 0, 0, 0);
        acc = __builtin_amdgcn_mfma_f32_16x16x32_bf16(al, w1h[t], acc, 0, 0, 0);
        acc = __builtin_amdgcn_mfma_f32_16x16x32_bf16(ah, w1l[t], acc, 0, 0, 0);
#pragma unroll
        for (int reg = 0; reg < 4; ++reg) {
          float a = acc[reg];
          a = fmaxf(a, 0.2f * a);           /* leaky 0.2 */
          sum[reg] = fmaf(a, w2r[t], sum[reg]);
        }
      }
#pragma unroll
      for (int reg = 0; reg < 4; ++reg) {
        float p = sum[reg];
        DPP_ADD(p, 0xB1,  0xf);             /* xor1 */
        DPP_ADD(p, 0x4E,  0xf);             /* xor2 */
        DPP_ADD(p, 0x141, 0xf);             /* xor4 (row_half_mirror) */
        DPP_ADD(p, 0x140, 0xf);             /* xor8 (row_mirror) */
        const int k = kt * 16 + (lg << 2) + reg;
        if (l16 == 0 && k < K_) ws[WS_LOG + (size_t)k * 32768 + bn] = p;
      }
    }
  }
}

/* ---------------- K2S: softmax + att + LDS-privatized W/W2 histograms ----- */
__global__ __launch_bounds__(256) void k2_softmax(float* __restrict__ ws) {
  __shared__ float h[4096];                 /* [0..2047]=W, [2048..4095]=W2 */
  const int i = blockIdx.x;                 /* 128 blocks */
  const int xcd = i & 7, j = i >> 3;        /* j 0..15 */
  const int b = 2 * xcd + (j & 1);
  const int half = j >> 1;                  /* 0..7 */
  const int bn = (b << 11) + (half << 8) + threadIdx.x;

#pragma unroll
  for (int q = 0; q < 16; ++q) h[threadIdx.x + (q << 8)] = 0.f;
  __syncthreads();

  float l[K_];
#pragma unroll
  for (int k = 0; k < K_; ++k) l[k] = ws[WS_LOG + (size_t)k * 32768 + bn];
  float mx = l[0];
#pragma unroll
  for (int k = 1; k < K_; ++k) mx = fmaxf(mx, l[k]);
  float den = 0.f;
#pragma unroll
  for (int k = 0; k < K_; ++k) { l[k] = __expf(l[k] - mx); den += l[k]; }
  const float inv = 1.f / den;
#pragma unroll
  for (int k = 0; k < K_; ++k) l[k] *= inv;

  float4* ap = (float4*)(ws + WS_ATT + (size_t)bn * K_);
#pragma unroll
  for (int q = 0; q < 6; ++q) {
    float4 v; v.x = l[4*q]; v.y = l[4*q+1]; v.z = l[4*q+2]; v.w = l[4*q+3];
    ap[q] = v;
  }
  const int* ip = (const int*)ws + WS_IDX + (size_t)bn * K_;
#pragma unroll
  for (int k = 0; k < K_; ++k) {
    const int mk = ip[k];
    atomicAdd(&h[mk], l[k]);                /* ds_add_f32 */
    atomicAdd(&h[2048 + mk], l[k] * l[k]);
  }
  __syncthreads();
  /* coalesced merge: 2048 bins x 2 arrays / 256 threads */
#pragma unroll
  for (int q = 0; q < 8; ++q) {
    const int m = threadIdx.x + (q << 8);
    atomicAdd(ws + WS_W  + (b << 11) + m, h[m]);
    atomicAdd(ws + WS_W2 + (b << 11) + m, h[2048 + m]);
  }
}

/* ---------------- K2B: BN stats from W/W2 (coalesced sweep) --------------- */
__global__ __launch_bounds__(256) void k2b_stats(float* __restrict__ ws) {
  __shared__ float ls[128];
  const int lane = threadIdx.x & 63;
  const int wv   = __builtin_amdgcn_readfirstlane(threadIdx.x >> 6);
  if (threadIdx.x < 128) ls[threadIdx.x] = 0.f;
  __syncthreads();
  const int i = blockIdx.x;                 /* 128 blocks */
  const int xcd = i & 7, j = i >> 3;
  const int b = 2 * xcd + (j & 1);
  const int half = j >> 1;
  const float* Y = ws + WS_Y;
  float s1 = 0.f, s2 = 0.f;
#pragma unroll 1
  for (int it = 0; it < 64; ++it) {
    const int m = (b << 11) + (half << 8) + (wv << 6) + it;   /* uniform */
    const float w  = ws[WS_W + m];           /* s_load */
    const float w2 = ws[WS_W2 + m];
    const float yv = Y[(size_t)m * 256 + 128 + lane];         /* coalesced */
    s1 = fmaf(w, yv, s1);
    s2 = fmaf(w2, yv * yv, s2);
  }
  atomicAdd(&ls[lane], s1);
  atomicAdd(&ls[64 + lane], s2);
  __syncthreads();
  if (threadIdx.x < 128) atomicAdd(ws + WS_ST + threadIdx.x, ls[threadIdx.x]);
}

/* ---------------- K4: BN finalize (inlined k3) + apply + residual + mean -- */
__global__ __launch_bounds__(256) void k4_out(float* __restrict__ out,
                                              const float* __restrict__ gam,
                                              const float* __restrict__ bet,
                                              const float* __restrict__ ws) {
  __shared__ float tile[32][65];
  const int lane = threadIdx.x & 63;
  const int wv   = __builtin_amdgcn_readfirstlane(threadIdx.x >> 6);
  const int i = blockIdx.x;                 /* 1024 blocks */
  const int xcd = i & 7, j = i >> 3;        /* j 0..127 */
  const int b = 2 * xcd + (j & 1);
  const int j2 = j >> 1;                    /* 0..63 */
  const int n0 = j2 << 5;                   /* 32-point tile */
  const float* Y = ws + WS_Y;

  /* inlined k3: per-lane BN scale/shift from global stats */
  float A, Bb;
  {
    const float s1 = ws[WS_ST + lane], s2 = ws[WS_ST + 64 + lane];
    const float cnt = (float)BNK_;
    const float mean = s1 / cnt;
    const float var = fmaxf(s2 / cnt - mean * mean, 0.f);
    A = gam[lane] / sqrtf(var + 1e-5f);
    Bb = bet[lane] - mean * A;
  }

#pragma unroll 1
  for (int pt = 0; pt < 8; ++pt) {
    const int bn = (b << 11) + n0 + (wv << 3) + pt;           /* uniform */
    const int*   ip = (const int*)ws + WS_IDX + (size_t)bn * K_;   /* s_load */
    const float* ap = ws + WS_ATT + (size_t)bn * K_;               /* s_load */
    float facc = 0.f, racc = 0.f;
#pragma unroll
    for (int k = 0; k < K_; ++k) {
      const int mk = ip[k];
      const float* row = Y + (size_t)((b << 11) + mk) * 256;
      float yv = row[128 + lane];           /* coalesced */
      float rv = row[192 + lane];           /* coalesced */
      float u = ap[k] * yv;
      float v = fmaf(u, A, Bb);
      v = v > 0.f ? v : 0.02f * v;          /* leaky 0.02 */
      facc += v;
      racc += rv;
    }
    tile[(wv << 3) + pt][lane] = (facc + 0.1f * racc) * (1.f / 24.f);
  }
  __syncthreads();
  const int o = threadIdx.x >> 2, q = threadIdx.x & 3;
  float* op = out + ((size_t)(b * 64 + o)) * 2048 + n0 + q * 8;
  float4 v0, v1;
  v0.x = tile[q*8+0][o]; v0.y = tile[q*8+1][o]; v0.z = tile[q*8+2][o]; v0.w = tile[q*8+3][o];
  v1.x = tile[q*8+4][o]; v1.y = tile[q*8+5][o]; v1.z = tile[q*8+6][o]; v1.w = tile[q*8+7][o];
  ((float4*)op)[0] = v0;
  ((float4*)op)[1] = v1;
}

extern "C" void kernel_launch(void* const* d_in, const int* in_sizes, int n_in,
                              void* d_out, int out_size, void* d_ws, size_t ws_size,
                              hipStream_t stream) {
  (void)in_sizes; (void)n_in; (void)out_size; (void)ws_size;
  const float* x    = (const float*)d_in[0];
  /* d_in[1] = idx_base (unused by reference) */
  const float* w1   = (const float*)d_in[2];
  const float* w2   = (const float*)d_in[3];
  const float* updw = (const float*)d_in[4];
  const float* bng  = (const float*)d_in[5];
  const float* bnb  = (const float*)d_in[6];
  const float* resw = (const float*)d_in[7];
  float* out = (float*)d_out;
  float* ws  = (float*)d_ws;

  k0_prep  <<<dim3(128),  dim3(256), 0, stream>>>(x, ws);
  k1a_mfma <<<dim3(2048), dim3(256), 0, stream>>>(ws);
  k1b_sel  <<<dim3(512),  dim3(64),  0, stream>>>(ws);
  kY       <<<dim3(1024), dim3(256), 0, stream>>>(w1, updw, resw, ws);
  k2_logits<<<dim3(2048), dim3(256), 0, stream>>>(w1, w2, ws);
  k2_softmax<<<dim3(128), dim3(256), 0, stream>>>(ws);
  k2b_stats<<<dim3(128),  dim3(256), 0, stream>>>(ws);
  k4_out   <<<dim3(1024), dim3(256), 0, stream>>>(out, bng, bnb, ws);
}

// Round 15
// 304.704 us; speedup vs baseline: 1.0167x; 1.0167x over previous
//
#include <hip/hip_runtime.h>
#include <math.h>

#define B_   16
#define C_   32
#define N_   2048
#define K_   24
#define BNK_ (B_*N_*K_)      /* 786432 */

typedef float vf2 __attribute__((ext_vector_type(2)));
typedef __attribute__((ext_vector_type(8))) short bf16x8;   /* 8 bf16 = 4 VGPRs */
typedef __attribute__((ext_vector_type(4))) float f32x4;

/* ws layout (float/int32 units), ~51 MB total (12,747,008 f) */
#define WS_XT   0u           /* xt[b][n][c]  : 1048576 f            */
#define WS_XXD  1048576u     /* xx fp64      : 65536 f              */
#define WS_XXF  1114112u     /* -xx/2 fp32   : 32768 f              */
#define WS_IDX  1146880u     /* idx[b][n][k] : 786432 i             */
#define WS_D2   1933312u     /* d2 [b][n][k] : 786432 f             */
#define WS_ATT  2719744u     /* att[b][n][k] : 786432 f             */
#define WS_LOG  3506176u     /* logitsT[k][bn]: 786432 f            */
#define WS_ST   4292608u     /* sum/sumsq    : 128 f                */
#define WS_AB   4292736u     /* BN A,B       : 128 f  (unused now)  */
#define WS_W    4292864u     /* W[m]  att-hist : 32768 f            */
#define WS_W2   4325632u     /* W2[m] att2-hist: 32768 f            */
#define WS_Y    4358400u     /* Y[m][256]: base|attn|upd|res : 8388608 f */
#define WS_L    4358400u     /* k1 lists 512*16*12*64 = 6291456 f
                                (aliases Y; dead before kY)         */
#define WS_HL   10649856u    /* bf16 hi/lo split [b*2048][16u32 hi|16u32 lo]
                                = 1048576 f; aliases Y tail; dead before kY */

__device__ __forceinline__ unsigned short bf16rne(float f) {
  unsigned int u = __float_as_uint(f);
  return (unsigned short)((u + 0x7FFFu + ((u >> 16) & 1u)) >> 16);
}

/* VALU-pipe cross-lane add via DPP (no DS ops). Masked lanes add 0. */
#define DPP_ADD(p, ctrl, rm)                                                  \
  (p) += __int_as_float(__builtin_amdgcn_update_dpp(                          \
      0, __float_as_int(p), (ctrl), (rm), 0xf, true))

/* ---------------- K0: transpose x -> xt, norms, bf16 hi/lo split ---------- */
__global__ __launch_bounds__(256) void k0_prep(const float* __restrict__ x,
                                               float* __restrict__ ws) {
  const int i = blockIdx.x;                 /* 128 blocks */
  const int xcd = i & 7, j = i >> 3;
  const int b = 2 * xcd + (j & 1);
  const int half = j >> 1;                  /* 0..7 */
  const int t = (b << 11) + (half << 8) + threadIdx.x;
  const int n = t & 2047;
  const float* xp = x + ((size_t)b * C_ * N_) + n;
  float4* xt4 = (float4*)(ws + WS_XT + (size_t)t * C_);
  uint4*  hl  = (uint4*)(ws + WS_HL) + (size_t)t * 8;
  unsigned int hu[16], lu[16];
  double s = 0.0;
#pragma unroll
  for (int cg = 0; cg < 8; ++cg) {
    float4 v;
    v.x = xp[(size_t)(4*cg  ) * N_];
    v.y = xp[(size_t)(4*cg+1) * N_];
    v.z = xp[(size_t)(4*cg+2) * N_];
    v.w = xp[(size_t)(4*cg+3) * N_];
    xt4[cg] = v;
    s = fma((double)v.x, (double)v.x, s);
    s = fma((double)v.y, (double)v.y, s);
    s = fma((double)v.z, (double)v.z, s);
    s = fma((double)v.w, (double)v.w, s);
    unsigned short h0 = bf16rne(v.x), h1 = bf16rne(v.y);
    unsigned short h2 = bf16rne(v.z), h3 = bf16rne(v.w);
    float l0 = v.x - __uint_as_float((unsigned int)h0 << 16);
    float l1 = v.y - __uint_as_float((unsigned int)h1 << 16);
    float l2 = v.z - __uint_as_float((unsigned int)h2 << 16);
    float l3 = v.w - __uint_as_float((unsigned int)h3 << 16);
    hu[2*cg]   = (unsigned int)h0 | ((unsigned int)h1 << 16);
    hu[2*cg+1] = (unsigned int)h2 | ((unsigned int)h3 << 16);
    lu[2*cg]   = (unsigned int)bf16rne(l0) | ((unsigned int)bf16rne(l1) << 16);
    lu[2*cg+1] = (unsigned int)bf16rne(l2) | ((unsigned int)bf16rne(l3) << 16);
  }
#pragma unroll
  for (int q = 0; q < 4; ++q) {
    uint4 hv; hv.x = hu[4*q]; hv.y = hu[4*q+1]; hv.z = hu[4*q+2]; hv.w = hu[4*q+3];
    hl[q] = hv;
    uint4 lv; lv.x = lu[4*q]; lv.y = lu[4*q+1]; lv.z = lu[4*q+2]; lv.w = lu[4*q+3];
    hl[4+q] = lv;
  }
  ((double*)(ws + WS_XXD))[t] = s;
  ws[WS_XXF + t] = -0.5f * (float)s;        /* NEGATED half-norm: acc init */
  ws[WS_W + t] = 0.f;
  ws[WS_W2 + t] = 0.f;
  if (t < 128) ws[WS_ST + t] = 0.f;
}

/* ---------------- K1a (MFMA + LDS-staged A-panel, 4 tiles/barrier) --------
   R14 keep: 4 tiles per barrier (8 barriers, 4x compute per vmcnt drain);
   neutral-to-positive vs 2-tile. 16KB LDS, 8 waves/SIMD preserved.        */
__global__ __launch_bounds__(256, 8) void k1a_mfma(float* __restrict__ ws) {
  __shared__ unsigned short tl[2][4096];    /* 2 x 8KB (4-tile) buffers */
  const int lane = threadIdx.x & 63;
  const int wv   = __builtin_amdgcn_readfirstlane(threadIdx.x >> 6);
  const int i = blockIdx.x;                 /* 2048 blocks */
  const int xcd = i & 7, j = i >> 3;        /* j 0..255 */
  const int b = 2 * xcd + (j & 1);
  const int j2 = j >> 1;                    /* 0..127 */
  const int nblk = j2 >> 2;                 /* 0..31 : 64-point group */
  const int mq   = j2 & 3;                  /* 0..3  : m quarter */
  const int l16 = lane & 15, lg = lane >> 4;

  const unsigned short* HL = (const unsigned short*)(ws + WS_HL) + ((size_t)b << 17);
  const int nrow = (nblk << 6) + (wv << 4) + l16;
  const bf16x8 bh = *(const bf16x8*)(HL + ((size_t)nrow << 6) + (lg << 3));
  const bf16x8 bl = *(const bf16x8*)(HL + ((size_t)nrow << 6) + 32 + (lg << 3));

  const int mbase = mq << 9;                /* 512-m quarter */
  const float4* nxx = (const float4*)(ws + WS_XXF + (b << 11) + mbase);

  /* staging source: lane covers row=lane>>3 (0..7) of a tile, slot=lane&7,
     source slot pre-swizzled so linear LDS dest ends up XOR-swizzled */
  const int srow = lane >> 3;
  const int sslot = (lane & 7) ^ srow;
  const unsigned short* Sp = HL + ((size_t)(mbase + srow) << 6) + (sslot << 3);

  /* reader LDS offsets (ushort units), same XOR involution */
  const int ah_off = (l16 << 6) + (((lg    ) ^ (l16 & 7)) << 3);
  const int al_off = (l16 << 6) + (((4 | lg) ^ (l16 & 7)) << 3);

  /* prologue: wave 0 stages tiles 0..3 into buf 0 */
  if (wv == 0) {
#pragma unroll
    for (int u = 0; u < 8; ++u) {
      const unsigned short* sp = Sp + ((size_t)(u >> 1) << 10) + (u & 1) * 512;
      __builtin_amdgcn_global_load_lds(
          (const __attribute__((address_space(1))) unsigned int*)(const void*)sp,
          (__attribute__((address_space(3))) unsigned int*)(void*)&tl[0][u * 512],
          16, 0, 0);
    }
  }
  __syncthreads();

  float val[12];
#pragma unroll
  for (int j0 = 0; j0 < 12; ++j0) val[j0] = -3.4e38f;
  int id = mbase + (lg << 2);               /* m of reg 0, tile 0 */

#pragma unroll 1
  for (int tt = 0; tt < 8; ++tt) {
    const int cur = tt & 1;
    if (tt < 7 && wv == (tt & 3)) {         /* rotating staging wave */
#pragma unroll
      for (int u = 0; u < 8; ++u) {
        const int tile = 4 * tt + 4 + (u >> 1);
        const unsigned short* sp = Sp + ((size_t)tile << 10) + (u & 1) * 512;
        __builtin_amdgcn_global_load_lds(
            (const __attribute__((address_space(1))) unsigned int*)(const void*)sp,
            (__attribute__((address_space(3))) unsigned int*)(void*)&tl[cur ^ 1][u * 512],
            16, 0, 0);
      }
    }
#pragma unroll
    for (int sub = 0; sub < 4; ++sub) {     /* four tiles from this buffer */
      const int t = 4 * tt + sub;
      const int base = sub << 10;
      bf16x8 ah = *(const bf16x8*)(&tl[cur][base + ah_off]);
      bf16x8 al = *(const bf16x8*)(&tl[cur][base + al_off]);
      float4 xq = nxx[(t << 2) + lg];       /* -xx/2 for this tile's 4 m's */
      f32x4 acc;
      acc[0] = xq.x; acc[1] = xq.y; acc[2] = xq.z; acc[3] = xq.w;
      acc = __builtin_amdgcn_mfma_f32_16x16x32_bf16(ah, bh, acc, 0, 0, 0);
      acc = __builtin_amdgcn_mfma_f32_16x16x32_bf16(al, bh, acc, 0, 0, 0);
      acc = __builtin_amdgcn_mfma_f32_16x16x32_bf16(ah, bl, acc, 0, 0, 0);
#pragma unroll
      for (int r = 0; r < 4; ++r) {
        int sb = (__float_as_int(acc[r]) & ~2047) | (id + r);
        float sp2 = __int_as_float(sb);
#pragma unroll
        for (int j0 = 11; j0 >= 1; --j0)
          val[j0] = __builtin_amdgcn_fmed3f(val[j0 - 1], val[j0], sp2);
        val[0] = fmaxf(val[0], sp2);
      }
      id += 16;
    }
    __syncthreads();                        /* drains vmcnt -> buf^1 ready */
  }
  /* subset slot = mq*4 + lane-group (16 slots); point-in-group = wv*16+l16 */
  const int pg = (b << 5) + nblk;
  float* Lp = ws + WS_L +
      (((size_t)pg * 16 + (mq << 2) + lg) * 12) * 64 + (wv << 4) + l16;
#pragma unroll
  for (int j0 = 0; j0 < 12; ++j0) Lp[(size_t)j0 * 64] = val[j0];
}

/* ---------------- K1b: union select (16x12=192) + exact fp64 re-rank ----- */
__global__ __launch_bounds__(64) void k1b_sel(float* __restrict__ ws) {
  const float* xt = ws + WS_XT;
  const double* xxd = (const double*)(ws + WS_XXD);
  const int lane = threadIdx.x & 63;
  const int i = blockIdx.x;                 /* 512 blocks */
  const int xcd = i & 7, j = i >> 3;        /* j 0..63 */
  const int b = 2 * xcd + (j & 1);
  const int sub = j >> 1;                   /* 0..31 */
  const int pg = (b << 5) + sub;
  const int bn = (b << 11) + (sub << 6) + lane;

  float val[28];
#pragma unroll
  for (int j0 = 0; j0 < 28; ++j0) val[j0] = -3.4e38f;
  const float* Lp = ws + WS_L + ((size_t)pg * 16 * 12) * 64 + lane;
#pragma unroll 4
  for (int t = 0; t < 192; ++t) {
    float sp = Lp[(size_t)t * 64];
#pragma unroll
    for (int j0 = 27; j0 >= 1; --j0)
      val[j0] = __builtin_amdgcn_fmed3f(val[j0 - 1], val[j0], sp);
    val[0] = fmaxf(val[0], sp);
  }

  double xnd[C_];
  {
    const float* p = xt + (size_t)bn * C_;
#pragma unroll
    for (int c = 0; c < C_; ++c) xnd[c] = (double)p[c];
  }
  double dl[K_];
#pragma unroll
  for (int j0 = 0; j0 < K_; ++j0) dl[j0] = -1.7e308;

#pragma unroll 1
  for (int j0 = 0; j0 < 28; ++j0) {
    const int m = __float_as_int(val[j0]) & 2047;
    const float* r = xt + ((size_t)((b << 11) + m)) * C_;
    double a0 = 0.0, a1 = 0.0;
#pragma unroll
    for (int c = 0; c < 16; ++c) {
      a0 = fma((double)r[c],      xnd[c],      a0);
      a1 = fma((double)r[c + 16], xnd[c + 16], a1);
    }
    double s = 2.0 * (a0 + a1) - xxd[(b << 11) + m];
    long long bits = (__double_as_longlong(s) & 0xFFFFFFFFFFFFF800ll) | (long long)m;
    double sp = __longlong_as_double(bits);
    if (sp > dl[K_ - 1]) {     /* guarded insert */
      bool c2 = true;
#pragma unroll
      for (int jj = K_ - 1; jj >= 1; --jj) {
        bool c1 = sp > dl[jj - 1];
        dl[jj] = c1 ? dl[jj - 1] : (c2 ? sp : dl[jj]);
        c2 = c1;
      }
      if (c2) dl[0] = sp;
    }
  }

  int*   op = (int*)ws + WS_IDX + (size_t)bn * K_;
  float* dp = ws + WS_D2 + (size_t)bn * K_;
  const double xxn = xxd[bn];
#pragma unroll
  for (int rr = 0; rr < K_; ++rr) {
    long long bl = __double_as_longlong(dl[rr]);
    op[rr] = (int)(bl & 0x7FFll);
    dp[rr] = (float)(xxn - __longlong_as_double(bl & 0xFFFFFFFFFFFFF800ll));
  }
}

/* ---------------- KY: Y[m] = [xt·w1c^T | xt·w1n^T | xt·updw^T | xt·resw^T] */
__global__ __launch_bounds__(256) void kY(const float* __restrict__ w1,
                                          const float* __restrict__ updw,
                                          const float* __restrict__ resw,
                                          float* __restrict__ ws) {
  const int lane = threadIdx.x & 63;
  const int wv   = __builtin_amdgcn_readfirstlane(threadIdx.x >> 6);
  const int i = blockIdx.x;                 /* 1024 blocks */
  const int xcd = i & 7, j = i >> 3;        /* j 0..127 */
  const int b = 2 * xcd + (j & 1);
  const int j2 = j >> 1;                    /* 0..63 */
  const int slot = (j2 << 2) | wv;          /* 0..255 */
  const int s  = slot & 7;                  /* slice 0..7 (uniform) */
  const int pg = slot >> 3;                 /* 0..31 */
  const int p = (b << 11) + (pg << 6) + lane;
  const float* xt = ws + WS_XT;

  float row[C_];
  {
    const float4* rp = (const float4*)(xt + (size_t)p * C_);
#pragma unroll
    for (int q = 0; q < 8; ++q) {
      float4 v = rp[q];
      row[4*q] = v.x; row[4*q+1] = v.y; row[4*q+2] = v.z; row[4*q+3] = v.w;
    }
  }
  const int part = s >> 1;                  /* 0..3 (uniform) */
  const int hch  = (s & 1) * 32;            /* first channel of slice */
  const float* W   = (part == 0) ? w1 : (part == 1) ? (w1 + 32)
                   : (part == 2) ? updw : resw;          /* uniform */
  const int stride = (part < 2) ? 80 : 32;
  float* yp = ws + WS_Y + (size_t)p * 256 + s * 32;
#pragma unroll 2
  for (int og = 0; og < 8; ++og) {
    float a[4] = {0.f, 0.f, 0.f, 0.f};
#pragma unroll
    for (int u = 0; u < 4; ++u) {
      const float* wr = W + (hch + 4 * og + u) * stride; /* uniform -> s_load */
#pragma unroll
      for (int c = 0; c < C_; ++c) a[u] = fmaf(row[c], wr[c], a[u]);
    }
    float4 st; st.x = a[0]; st.y = a[1]; st.z = a[2]; st.w = a[3];
    ((float4*)yp)[og] = st;
  }
}

/* ---------------- K2L: logits via 16x16x32 split-MFMA ---------------------
   R15: full revert of k2L to the proven R13 structure (in-loop rv reads,
   rne hi-split) — R14's reg-array ILP hoist caused mild spill (VGPR 64,
   WRITE 3.1->14.8MB, +2.5us). Only change vs R13: drop the redundant
   &2047 masks on mk (k1b guarantees idx<2048).                            */
__global__ __launch_bounds__(256, 4) void k2_logits(const float* __restrict__ w1,
                                                    const float* __restrict__ w2,
                                                    float* __restrict__ ws) {
  __shared__ unsigned short A_s[4][2048];   /* [wave][32 rows][hi32|lo32] 16KB */
  __shared__ float dist_s[4][24];
  const int lane = threadIdx.x & 63;
  const int wv   = __builtin_amdgcn_readfirstlane(threadIdx.x >> 6);
  const int l16 = lane & 15, lg = lane >> 4;
  const int i = blockIdx.x;                 /* 2048 blocks */
  const int xcd = i & 7, j = i >> 3;        /* j 0..255 */
  const int b = 2 * xcd + (j & 1);
  const int grp = j >> 1;                   /* 0..127 : 16-point group */
  const float* Y = ws + WS_Y;

  /* zero A (rows 24..31 and r>=16 slots stay zero forever) */
  {
    uint4 z; z.x = 0; z.y = 0; z.z = 0; z.w = 0;
    uint4* az = (uint4*)&A_s[wv][0];
    az[lane] = z; az[lane + 64] = z; az[lane + 128] = z; az[lane + 192] = z;
  }

  /* W1 B-fragments (hi/lo x 4 o-tiles): lane = o-col l16, elems r=lg*8..+7 */
  bf16x8 w1h[4], w1l[4];
  float w2r[4];
#pragma unroll
  for (int t = 0; t < 4; ++t) {
    const int o = t * 16 + l16;
    w2r[t] = w2[o];
    bf16x8 vh, vl;
#pragma unroll
    for (int jj = 0; jj < 8; ++jj) {
      const int r = lg * 8 + jj;
      float v = (r < 16) ? w1[o * 80 + 64 + r] : 0.f;
      unsigned short h = bf16rne(v);
      float lo = v - __uint_as_float((unsigned int)h << 16);
      vh[jj] = (short)h;
      vl[jj] = (short)bf16rne(lo);
    }
    w1h[t] = vh; w1l[t] = vl;
  }

#pragma unroll 1
  for (int q = 0; q < 4; ++q) {
    const int bn = (b << 11) + (grp << 4) + (wv << 2) + q;        /* uniform */
    const float* dpp = ws + WS_D2 + (size_t)bn * K_;
    if (lane < K_) dist_s[wv][lane] = sqrtf(fmaxf(dpp[lane], 1e-12f));
    /* rbf -> bf16 hi/lo into A rows: 3 (k,r-pair) items per lane */
#pragma unroll
    for (int t = 0; t < 3; ++t) {
      const int f2 = lane + (t << 6);       /* 0..191 = k*8 + r2 */
      const int k = f2 >> 3, r2 = f2 & 7;
      const float d = dist_s[wv][k];
      float d0 = d - (float)(2 * r2    ) * (5.0f / 15.0f);
      float d1 = d - (float)(2 * r2 + 1) * (5.0f / 15.0f);
      float e0 = fminf(fmaxf(__expf(-10.f * d0 * d0), 1e-10f), 1.0f);
      float e1 = fminf(fmaxf(__expf(-10.f * d1 * d1), 1e-10f), 1.0f);
      unsigned short h0 = bf16rne(e0), h1 = bf16rne(e1);
      float lo0 = e0 - __uint_as_float((unsigned int)h0 << 16);
      float lo1 = e1 - __uint_as_float((unsigned int)h1 << 16);
      unsigned short g0 = bf16rne(lo0), g1 = bf16rne(lo1);
      const int slot = r2 >> 2;             /* logical hi slot 0..1 */
      const int us = (2 * r2) & 7;          /* even ushort within slot */
      const int ph = (slot     ^ (k & 7));
      const int pl = ((4|slot) ^ (k & 7));
      *(unsigned int*)&A_s[wv][(k << 6) + (ph << 3) + us] =
          (unsigned int)h0 | ((unsigned int)h1 << 16);
      *(unsigned int*)&A_s[wv][(k << 6) + (pl << 3) + us] =
          (unsigned int)g0 | ((unsigned int)g1 << 16);
    }
    /* ba[o] per o-tile (coalesced) */
    float ba[4];
#pragma unroll
    for (int t = 0; t < 4; ++t) ba[t] = Y[(size_t)bn * 256 + t * 16 + l16];

#pragma unroll
    for (int kt = 0; kt < 2; ++kt) {
      const int row = kt * 16 + l16;
      bf16x8 ah = *(const bf16x8*)&A_s[wv][(row << 6) + (((lg    ) ^ (row & 7)) << 3)];
      bf16x8 al = *(const bf16x8*)&A_s[wv][(row << 6) + (((4 | lg) ^ (row & 7)) << 3)];
      /* neighbor indices for this lane's 4 k's (k = kt*16 + lg*4 + reg) */
      int mk[4];
#pragma unroll
      for (int reg = 0; reg < 4; ++reg) {
        const int k = kt * 16 + (lg << 2) + reg;
        mk[reg] = ((const int*)ws)[WS_IDX + (size_t)bn * K_ + (k < K_ ? k : 0)];
      }
      float sum[4] = {0.f, 0.f, 0.f, 0.f};
#pragma unroll
      for (int t = 0; t < 4; ++t) {
        f32x4 acc;
#pragma unroll
        for (int reg = 0; reg < 4; ++reg) {
          float rv = Y[(size_t)((b << 11) + mk[reg]) * 256 + 64 + t * 16 + l16];
          acc[reg] = ba[t] + rv;            /* C init = ba + rv */
        }
        acc = __builtin_amdgcn_mfma_f32_16x16x32_bf16(ah, w1h[t], acc, 0, 0, 0);
        acc = __builtin_amdgcn_mfma_f32_16x16x32_bf16(al, w1h[t], acc, 0, 0, 0);
        acc = __builtin_amdgcn_mfma_f32_16x16x32_bf16(ah, w1l[t], acc, 0, 0, 0);
#pragma unroll
        for (int reg = 0; reg < 4; ++reg) {
          float a = acc[reg];
          a = fmaxf(a, 0.2f * a);           /* leaky 0.2 */
          sum[reg] = fmaf(a, w2r[t], sum[reg]);
        }
      }
#pragma unroll
      for (int reg = 0; reg < 4; ++reg) {
        float p = sum[reg];
        DPP_ADD(p, 0xB1,  0xf);             /* xor1 */
        DPP_ADD(p, 0x4E,  0xf);             /* xor2 */
        DPP_ADD(p, 0x141, 0xf);             /* xor4 (row_half_mirror) */
        DPP_ADD(p, 0x140, 0xf);             /* xor8 (row_mirror) */
        const int k = kt * 16 + (lg << 2) + reg;
        if (l16 == 0 && k < K_) ws[WS_LOG + (size_t)k * 32768 + bn] = p;
      }
    }
  }
}

/* ---------------- K2S: softmax + att + LDS-privatized W/W2 histograms ----- */
__global__ __launch_bounds__(256) void k2_softmax(float* __restrict__ ws) {
  __shared__ float h[4096];                 /* [0..2047]=W, [2048..4095]=W2 */
  const int i = blockIdx.x;                 /* 128 blocks */
  const int xcd = i & 7, j = i >> 3;        /* j 0..15 */
  const int b = 2 * xcd + (j & 1);
  const int half = j >> 1;                  /* 0..7 */
  const int bn = (b << 11) + (half << 8) + threadIdx.x;

#pragma unroll
  for (int q = 0; q < 16; ++q) h[threadIdx.x + (q << 8)] = 0.f;
  __syncthreads();

  float l[K_];
#pragma unroll
  for (int k = 0; k < K_; ++k) l[k] = ws[WS_LOG + (size_t)k * 32768 + bn];
  float mx = l[0];
#pragma unroll
  for (int k = 1; k < K_; ++k) mx = fmaxf(mx, l[k]);
  float den = 0.f;
#pragma unroll
  for (int k = 0; k < K_; ++k) { l[k] = __expf(l[k] - mx); den += l[k]; }
  const float inv = 1.f / den;
#pragma unroll
  for (int k = 0; k < K_; ++k) l[k] *= inv;

  float4* ap = (float4*)(ws + WS_ATT + (size_t)bn * K_);
#pragma unroll
  for (int q = 0; q < 6; ++q) {
    float4 v; v.x = l[4*q]; v.y = l[4*q+1]; v.z = l[4*q+2]; v.w = l[4*q+3];
    ap[q] = v;
  }
  const int* ip = (const int*)ws + WS_IDX + (size_t)bn * K_;
#pragma unroll
  for (int k = 0; k < K_; ++k) {
    const int mk = ip[k];
    atomicAdd(&h[mk], l[k]);                /* ds_add_f32 */
    atomicAdd(&h[2048 + mk], l[k] * l[k]);
  }
  __syncthreads();
  /* coalesced merge: 2048 bins x 2 arrays / 256 threads */
#pragma unroll
  for (int q = 0; q < 8; ++q) {
    const int m = threadIdx.x + (q << 8);
    atomicAdd(ws + WS_W  + (b << 11) + m, h[m]);
    atomicAdd(ws + WS_W2 + (b << 11) + m, h[2048 + m]);
  }
}

/* ---------------- K2B: BN stats from W/W2 (coalesced sweep) --------------- */
__global__ __launch_bounds__(256) void k2b_stats(float* __restrict__ ws) {
  __shared__ float ls[128];
  const int lane = threadIdx.x & 63;
  const int wv   = __builtin_amdgcn_readfirstlane(threadIdx.x >> 6);
  if (threadIdx.x < 128) ls[threadIdx.x] = 0.f;
  __syncthreads();
  const int i = blockIdx.x;                 /* 128 blocks */
  const int xcd = i & 7, j = i >> 3;
  const int b = 2 * xcd + (j & 1);
  const int half = j >> 1;
  const float* Y = ws + WS_Y;
  float s1 = 0.f, s2 = 0.f;
#pragma unroll 1
  for (int it = 0; it < 64; ++it) {
    const int m = (b << 11) + (half << 8) + (wv << 6) + it;   /* uniform */
    const float w  = ws[WS_W + m];           /* s_load */
    const float w2 = ws[WS_W2 + m];
    const float yv = Y[(size_t)m * 256 + 128 + lane];         /* coalesced */
    s1 = fmaf(w, yv, s1);
    s2 = fmaf(w2, yv * yv, s2);
  }
  atomicAdd(&ls[lane], s1);
  atomicAdd(&ls[64 + lane], s2);
  __syncthreads();
  if (threadIdx.x < 128) atomicAdd(ws + WS_ST + threadIdx.x, ls[threadIdx.x]);
}

/* ---------------- K4: BN finalize (inlined k3) + apply + residual + mean -- */
__global__ __launch_bounds__(256) void k4_out(float* __restrict__ out,
                                              const float* __restrict__ gam,
                                              const float* __restrict__ bet,
                                              const float* __restrict__ ws) {
  __shared__ float tile[32][65];
  const int lane = threadIdx.x & 63;
  const int wv   = __builtin_amdgcn_readfirstlane(threadIdx.x >> 6);
  const int i = blockIdx.x;                 /* 1024 blocks */
  const int xcd = i & 7, j = i >> 3;        /* j 0..127 */
  const int b = 2 * xcd + (j & 1);
  const int j2 = j >> 1;                    /* 0..63 */
  const int n0 = j2 << 5;                   /* 32-point tile */
  const float* Y = ws + WS_Y;

  /* inlined k3: per-lane BN scale/shift from global stats */
  float A, Bb;
  {
    const float s1 = ws[WS_ST + lane], s2 = ws[WS_ST + 64 + lane];
    const float cnt = (float)BNK_;
    const float mean = s1 / cnt;
    const float var = fmaxf(s2 / cnt - mean * mean, 0.f);
    A = gam[lane] / sqrtf(var + 1e-5f);
    Bb = bet[lane] - mean * A;
  }

#pragma unroll 1
  for (int pt = 0; pt < 8; ++pt) {
    const int bn = (b << 11) + n0 + (wv << 3) + pt;           /* uniform */
    const int*   ip = (const int*)ws + WS_IDX + (size_t)bn * K_;   /* s_load */
    const float* ap = ws + WS_ATT + (size_t)bn * K_;               /* s_load */
    float facc = 0.f, racc = 0.f;
#pragma unroll
    for (int k = 0; k < K_; ++k) {
      const int mk = ip[k];
      const float* row = Y + (size_t)((b << 11) + mk) * 256;
      float yv = row[128 + lane];           /* coalesced */
      float rv = row[192 + lane];           /* coalesced */
      float u = ap[k] * yv;
      float v = fmaf(u, A, Bb);
      v = v > 0.f ? v : 0.02f * v;          /* leaky 0.02 */
      facc += v;
      racc += rv;
    }
    tile[(wv << 3) + pt][lane] = (facc + 0.1f * racc) * (1.f / 24.f);
  }
  __syncthreads();
  const int o = threadIdx.x >> 2, q = threadIdx.x & 3;
  float* op = out + ((size_t)(b * 64 + o)) * 2048 + n0 + q * 8;
  float4 v0, v1;
  v0.x = tile[q*8+0][o]; v0.y = tile[q*8+1][o]; v0.z = tile[q*8+2][o]; v0.w = tile[q*8+3][o];
  v1.x = tile[q*8+4][o]; v1.y = tile[q*8+5][o]; v1.z = tile[q*8+6][o]; v1.w = tile[q*8+7][o];
  ((float4*)op)[0] = v0;
  ((float4*)op)[1] = v1;
}

extern "C" void kernel_launch(void* const* d_in, const int* in_sizes, int n_in,
                              void* d_out, int out_size, void* d_ws, size_t ws_size,
                              hipStream_t stream) {
  (void)in_sizes; (void)n_in; (void)out_size; (void)ws_size;
  const float* x    = (const float*)d_in[0];
  /* d_in[1] = idx_base (unused by reference) */
  const float* w1   = (const float*)d_in[2];
  const float* w2   = (const float*)d_in[3];
  const float* updw = (const float*)d_in[4];
  const float* bng  = (const float*)d_in[5];
  const float* bnb  = (const float*)d_in[6];
  const float* resw = (const float*)d_in[7];
  float* out = (float*)d_out;
  float* ws  = (float*)d_ws;

  k0_prep  <<<dim3(128),  dim3(256), 0, stream>>>(x, ws);
  k1a_mfma <<<dim3(2048), dim3(256), 0, stream>>>(ws);
  k1b_sel  <<<dim3(512),  dim3(64),  0, stream>>>(ws);
  kY       <<<dim3(1024), dim3(256), 0, stream>>>(w1, updw, resw, ws);
  k2_logits<<<dim3(2048), dim3(256), 0, stream>>>(w1, w2, ws);
  k2_softmax<<<dim3(128), dim3(256), 0, stream>>>(ws);
  k2b_stats<<<dim3(128),  dim3(256), 0, stream>>>(ws);
  k4_out   <<<dim3(1024), dim3(256), 0, stream>>>(out, bng, bnb, ws);
}

// Round 16
// 293.926 us; speedup vs baseline: 1.0540x; 1.0367x over previous
//
#include <hip/hip_runtime.h>
#include <math.h>

#define B_   16
#define C_   32
#define N_   2048
#define K_   24
#define BNK_ (B_*N_*K_)      /* 786432 */

typedef float vf2 __attribute__((ext_vector_type(2)));
typedef __attribute__((ext_vector_type(8))) short bf16x8;   /* 8 bf16 = 4 VGPRs */
typedef __attribute__((ext_vector_type(4))) float f32x4;

/* ws layout (float/int32 units), ~51 MB total (12,747,008 f) */
#define WS_XT   0u           /* xt[b][n][c]  : 1048576 f            */
#define WS_XXD  1048576u     /* xx fp64      : 65536 f              */
#define WS_XXF  1114112u     /* -xx/2 fp32   : 32768 f              */
#define WS_IDX  1146880u     /* idx[b][n][k] : 786432 i             */
#define WS_D2   1933312u     /* d2 [b][n][k] : 786432 f             */
#define WS_ATT  2719744u     /* att[b][n][k] : 786432 f             */
#define WS_LOG  3506176u     /* logitsT[k][bn]: 786432 f            */
#define WS_ST   4292608u     /* sum/sumsq    : 128 f                */
#define WS_AB   4292736u     /* BN A,B       : 128 f  (unused now)  */
#define WS_W    4292864u     /* W[m]  att-hist : 32768 f            */
#define WS_W2   4325632u     /* W2[m] att2-hist: 32768 f            */
#define WS_Y    4358400u     /* Y[m][256]: base|attn|upd|res : 8388608 f */
#define WS_L    4358400u     /* k1 lists 512*16*12*64 = 6291456 f
                                (aliases Y; dead before kY)         */
#define WS_HL   10649856u    /* bf16 hi/lo split [b*2048][16u32 hi|16u32 lo]
                                = 1048576 f; aliases Y tail; dead before kY */

__device__ __forceinline__ unsigned short bf16rne(float f) {
  unsigned int u = __float_as_uint(f);
  return (unsigned short)((u + 0x7FFFu + ((u >> 16) & 1u)) >> 16);
}

/* VALU-pipe cross-lane add via DPP (no DS ops). Masked lanes add 0. */
#define DPP_ADD(p, ctrl, rm)                                                  \
  (p) += __int_as_float(__builtin_amdgcn_update_dpp(                          \
      0, __float_as_int(p), (ctrl), (rm), 0xf, true))

/* ---------------- K0: transpose x -> xt, norms, bf16 hi/lo split ---------- */
__global__ __launch_bounds__(256) void k0_prep(const float* __restrict__ x,
                                               float* __restrict__ ws) {
  const int i = blockIdx.x;                 /* 128 blocks */
  const int xcd = i & 7, j = i >> 3;
  const int b = 2 * xcd + (j & 1);
  const int half = j >> 1;                  /* 0..7 */
  const int t = (b << 11) + (half << 8) + threadIdx.x;
  const int n = t & 2047;
  const float* xp = x + ((size_t)b * C_ * N_) + n;
  float4* xt4 = (float4*)(ws + WS_XT + (size_t)t * C_);
  uint4*  hl  = (uint4*)(ws + WS_HL) + (size_t)t * 8;
  unsigned int hu[16], lu[16];
  double s = 0.0;
#pragma unroll
  for (int cg = 0; cg < 8; ++cg) {
    float4 v;
    v.x = xp[(size_t)(4*cg  ) * N_];
    v.y = xp[(size_t)(4*cg+1) * N_];
    v.z = xp[(size_t)(4*cg+2) * N_];
    v.w = xp[(size_t)(4*cg+3) * N_];
    xt4[cg] = v;
    s = fma((double)v.x, (double)v.x, s);
    s = fma((double)v.y, (double)v.y, s);
    s = fma((double)v.z, (double)v.z, s);
    s = fma((double)v.w, (double)v.w, s);
    unsigned short h0 = bf16rne(v.x), h1 = bf16rne(v.y);
    unsigned short h2 = bf16rne(v.z), h3 = bf16rne(v.w);
    float l0 = v.x - __uint_as_float((unsigned int)h0 << 16);
    float l1 = v.y - __uint_as_float((unsigned int)h1 << 16);
    float l2 = v.z - __uint_as_float((unsigned int)h2 << 16);
    float l3 = v.w - __uint_as_float((unsigned int)h3 << 16);
    hu[2*cg]   = (unsigned int)h0 | ((unsigned int)h1 << 16);
    hu[2*cg+1] = (unsigned int)h2 | ((unsigned int)h3 << 16);
    lu[2*cg]   = (unsigned int)bf16rne(l0) | ((unsigned int)bf16rne(l1) << 16);
    lu[2*cg+1] = (unsigned int)bf16rne(l2) | ((unsigned int)bf16rne(l3) << 16);
  }
#pragma unroll
  for (int q = 0; q < 4; ++q) {
    uint4 hv; hv.x = hu[4*q]; hv.y = hu[4*q+1]; hv.z = hu[4*q+2]; hv.w = hu[4*q+3];
    hl[q] = hv;
    uint4 lv; lv.x = lu[4*q]; lv.y = lu[4*q+1]; lv.z = lu[4*q+2]; lv.w = lu[4*q+3];
    hl[4+q] = lv;
  }
  ((double*)(ws + WS_XXD))[t] = s;
  ws[WS_XXF + t] = -0.5f * (float)s;        /* NEGATED half-norm: acc init */
  ws[WS_W + t] = 0.f;
  ws[WS_W2 + t] = 0.f;
  if (t < 128) ws[WS_ST + t] = 0.f;
}

/* ---------------- K1a (MFMA + LDS-staged A-panel, 4 tiles/barrier) -------- */
__global__ __launch_bounds__(256, 8) void k1a_mfma(float* __restrict__ ws) {
  __shared__ unsigned short tl[2][4096];    /* 2 x 8KB (4-tile) buffers */
  const int lane = threadIdx.x & 63;
  const int wv   = __builtin_amdgcn_readfirstlane(threadIdx.x >> 6);
  const int i = blockIdx.x;                 /* 2048 blocks */
  const int xcd = i & 7, j = i >> 3;        /* j 0..255 */
  const int b = 2 * xcd + (j & 1);
  const int j2 = j >> 1;                    /* 0..127 */
  const int nblk = j2 >> 2;                 /* 0..31 : 64-point group */
  const int mq   = j2 & 3;                  /* 0..3  : m quarter */
  const int l16 = lane & 15, lg = lane >> 4;

  const unsigned short* HL = (const unsigned short*)(ws + WS_HL) + ((size_t)b << 17);
  const int nrow = (nblk << 6) + (wv << 4) + l16;
  const bf16x8 bh = *(const bf16x8*)(HL + ((size_t)nrow << 6) + (lg << 3));
  const bf16x8 bl = *(const bf16x8*)(HL + ((size_t)nrow << 6) + 32 + (lg << 3));

  const int mbase = mq << 9;                /* 512-m quarter */
  const float4* nxx = (const float4*)(ws + WS_XXF + (b << 11) + mbase);

  /* staging source: lane covers row=lane>>3 (0..7) of a tile, slot=lane&7,
     source slot pre-swizzled so linear LDS dest ends up XOR-swizzled */
  const int srow = lane >> 3;
  const int sslot = (lane & 7) ^ srow;
  const unsigned short* Sp = HL + ((size_t)(mbase + srow) << 6) + (sslot << 3);

  /* reader LDS offsets (ushort units), same XOR involution */
  const int ah_off = (l16 << 6) + (((lg    ) ^ (l16 & 7)) << 3);
  const int al_off = (l16 << 6) + (((4 | lg) ^ (l16 & 7)) << 3);

  /* prologue: wave 0 stages tiles 0..3 into buf 0 */
  if (wv == 0) {
#pragma unroll
    for (int u = 0; u < 8; ++u) {
      const unsigned short* sp = Sp + ((size_t)(u >> 1) << 10) + (u & 1) * 512;
      __builtin_amdgcn_global_load_lds(
          (const __attribute__((address_space(1))) unsigned int*)(const void*)sp,
          (__attribute__((address_space(3))) unsigned int*)(void*)&tl[0][u * 512],
          16, 0, 0);
    }
  }
  __syncthreads();

  float val[12];
#pragma unroll
  for (int j0 = 0; j0 < 12; ++j0) val[j0] = -3.4e38f;
  int id = mbase + (lg << 2);               /* m of reg 0, tile 0 */

#pragma unroll 1
  for (int tt = 0; tt < 8; ++tt) {
    const int cur = tt & 1;
    if (tt < 7 && wv == (tt & 3)) {         /* rotating staging wave */
#pragma unroll
      for (int u = 0; u < 8; ++u) {
        const int tile = 4 * tt + 4 + (u >> 1);
        const unsigned short* sp = Sp + ((size_t)tile << 10) + (u & 1) * 512;
        __builtin_amdgcn_global_load_lds(
            (const __attribute__((address_space(1))) unsigned int*)(const void*)sp,
            (__attribute__((address_space(3))) unsigned int*)(void*)&tl[cur ^ 1][u * 512],
            16, 0, 0);
      }
    }
#pragma unroll
    for (int sub = 0; sub < 4; ++sub) {     /* four tiles from this buffer */
      const int t = 4 * tt + sub;
      const int base = sub << 10;
      bf16x8 ah = *(const bf16x8*)(&tl[cur][base + ah_off]);
      bf16x8 al = *(const bf16x8*)(&tl[cur][base + al_off]);
      float4 xq = nxx[(t << 2) + lg];       /* -xx/2 for this tile's 4 m's */
      f32x4 acc;
      acc[0] = xq.x; acc[1] = xq.y; acc[2] = xq.z; acc[3] = xq.w;
      acc = __builtin_amdgcn_mfma_f32_16x16x32_bf16(ah, bh, acc, 0, 0, 0);
      acc = __builtin_amdgcn_mfma_f32_16x16x32_bf16(al, bh, acc, 0, 0, 0);
      acc = __builtin_amdgcn_mfma_f32_16x16x32_bf16(ah, bl, acc, 0, 0, 0);
#pragma unroll
      for (int r = 0; r < 4; ++r) {
        int sb = (__float_as_int(acc[r]) & ~2047) | (id + r);
        float sp2 = __int_as_float(sb);
#pragma unroll
        for (int j0 = 11; j0 >= 1; --j0)
          val[j0] = __builtin_amdgcn_fmed3f(val[j0 - 1], val[j0], sp2);
        val[0] = fmaxf(val[0], sp2);
      }
      id += 16;
    }
    __syncthreads();                        /* drains vmcnt -> buf^1 ready */
  }
  /* subset slot = mq*4 + lane-group (16 slots); point-in-group = wv*16+l16 */
  const int pg = (b << 5) + nblk;
  float* Lp = ws + WS_L +
      (((size_t)pg * 16 + (mq << 2) + lg) * 12) * 64 + (wv << 4) + l16;
#pragma unroll
  for (int j0 = 0; j0 < 12; ++j0) Lp[(size_t)j0 * 64] = val[j0];
}

/* ---------------- K1b: 4-wave cooperative union select + fp64 re-rank -----
   R16: old k1b was 512 blocks x 64 threads = 0.5 waves/SIMD (Occupancy
   4.8%!), one giant serial med3 chain + 192 dependent loads, pure latency
   exposure (47.5us at VALUBusy 17%). Now 512 x 256: wave w scans its 48
   of the 192 union entries into a depth-28 list (exact: a global-top-28
   element is top-28 within its wave's share); waves 1-3 park lists in LDS;
   wave 0 merges by re-insertion (84x28 med3) then runs the identical fp64
   re-rank. 4x parallel scan, 2 waves/SIMD.                                */
__global__ __launch_bounds__(256) void k1b_sel(float* __restrict__ ws) {
  __shared__ float ls[3][28][64];           /* waves 1..3 lists: 21.5KB */
  const float* xt = ws + WS_XT;
  const double* xxd = (const double*)(ws + WS_XXD);
  const int lane = threadIdx.x & 63;
  const int wv   = threadIdx.x >> 6;        /* 0..3 */
  const int i = blockIdx.x;                 /* 512 blocks */
  const int xcd = i & 7, j = i >> 3;        /* j 0..63 */
  const int b = 2 * xcd + (j & 1);
  const int sub = j >> 1;                   /* 0..31 */
  const int pg = (b << 5) + sub;
  const int bn = (b << 11) + (sub << 6) + lane;

  /* phase 1: each wave scans its contiguous 48 entries, depth-28 insert */
  float val[28];
#pragma unroll
  for (int j0 = 0; j0 < 28; ++j0) val[j0] = -3.4e38f;
  const float* Lp = ws + WS_L + ((size_t)pg * 192 + (size_t)wv * 48) * 64 + lane;
#pragma unroll 4
  for (int t = 0; t < 48; ++t) {
    float sp = Lp[(size_t)t * 64];
#pragma unroll
    for (int j0 = 27; j0 >= 1; --j0)
      val[j0] = __builtin_amdgcn_fmed3f(val[j0 - 1], val[j0], sp);
    val[0] = fmaxf(val[0], sp);
  }
  /* phase 2: waves 1..3 park lists in LDS and exit */
  if (wv != 0) {
#pragma unroll
    for (int j0 = 0; j0 < 28; ++j0) ls[wv - 1][j0][lane] = val[j0];
  }
  __syncthreads();
  if (wv != 0) return;

  /* phase 3: wave 0 merges the 3 foreign lists by re-insertion */
#pragma unroll 1
  for (int w = 0; w < 3; ++w) {
#pragma unroll 4
    for (int t = 0; t < 28; ++t) {
      float sp = ls[w][t][lane];
#pragma unroll
      for (int j0 = 27; j0 >= 1; --j0)
        val[j0] = __builtin_amdgcn_fmed3f(val[j0 - 1], val[j0], sp);
      val[0] = fmaxf(val[0], sp);
    }
  }

  /* phase 4: identical exact fp64 re-rank */
  double xnd[C_];
  {
    const float* p = xt + (size_t)bn * C_;
#pragma unroll
    for (int c = 0; c < C_; ++c) xnd[c] = (double)p[c];
  }
  double dl[K_];
#pragma unroll
  for (int j0 = 0; j0 < K_; ++j0) dl[j0] = -1.7e308;

#pragma unroll 1
  for (int j0 = 0; j0 < 28; ++j0) {
    const int m = __float_as_int(val[j0]) & 2047;
    const float* r = xt + ((size_t)((b << 11) + m)) * C_;
    double a0 = 0.0, a1 = 0.0;
#pragma unroll
    for (int c = 0; c < 16; ++c) {
      a0 = fma((double)r[c],      xnd[c],      a0);
      a1 = fma((double)r[c + 16], xnd[c + 16], a1);
    }
    double s = 2.0 * (a0 + a1) - xxd[(b << 11) + m];
    long long bits = (__double_as_longlong(s) & 0xFFFFFFFFFFFFF800ll) | (long long)m;
    double sp = __longlong_as_double(bits);
    if (sp > dl[K_ - 1]) {     /* guarded insert */
      bool c2 = true;
#pragma unroll
      for (int jj = K_ - 1; jj >= 1; --jj) {
        bool c1 = sp > dl[jj - 1];
        dl[jj] = c1 ? dl[jj - 1] : (c2 ? sp : dl[jj]);
        c2 = c1;
      }
      if (c2) dl[0] = sp;
    }
  }

  int*   op = (int*)ws + WS_IDX + (size_t)bn * K_;
  float* dp = ws + WS_D2 + (size_t)bn * K_;
  const double xxn = xxd[bn];
#pragma unroll
  for (int rr = 0; rr < K_; ++rr) {
    long long bl = __double_as_longlong(dl[rr]);
    op[rr] = (int)(bl & 0x7FFll);
    dp[rr] = (float)(xxn - __longlong_as_double(bl & 0xFFFFFFFFFFFFF800ll));
  }
}

/* ---------------- KY: Y[m] = [xt·w1c^T | xt·w1n^T | xt·updw^T | xt·resw^T] */
__global__ __launch_bounds__(256) void kY(const float* __restrict__ w1,
                                          const float* __restrict__ updw,
                                          const float* __restrict__ resw,
                                          float* __restrict__ ws) {
  const int lane = threadIdx.x & 63;
  const int wv   = __builtin_amdgcn_readfirstlane(threadIdx.x >> 6);
  const int i = blockIdx.x;                 /* 1024 blocks */
  const int xcd = i & 7, j = i >> 3;        /* j 0..127 */
  const int b = 2 * xcd + (j & 1);
  const int j2 = j >> 1;                    /* 0..63 */
  const int slot = (j2 << 2) | wv;          /* 0..255 */
  const int s  = slot & 7;                  /* slice 0..7 (uniform) */
  const int pg = slot >> 3;                 /* 0..31 */
  const int p = (b << 11) + (pg << 6) + lane;
  const float* xt = ws + WS_XT;

  float row[C_];
  {
    const float4* rp = (const float4*)(xt + (size_t)p * C_);
#pragma unroll
    for (int q = 0; q < 8; ++q) {
      float4 v = rp[q];
      row[4*q] = v.x; row[4*q+1] = v.y; row[4*q+2] = v.z; row[4*q+3] = v.w;
    }
  }
  const int part = s >> 1;                  /* 0..3 (uniform) */
  const int hch  = (s & 1) * 32;            /* first channel of slice */
  const float* W   = (part == 0) ? w1 : (part == 1) ? (w1 + 32)
                   : (part == 2) ? updw : resw;          /* uniform */
  const int stride = (part < 2) ? 80 : 32;
  float* yp = ws + WS_Y + (size_t)p * 256 + s * 32;
#pragma unroll 2
  for (int og = 0; og < 8; ++og) {
    float a[4] = {0.f, 0.f, 0.f, 0.f};
#pragma unroll
    for (int u = 0; u < 4; ++u) {
      const float* wr = W + (hch + 4 * og + u) * stride; /* uniform -> s_load */
#pragma unroll
      for (int c = 0; c < C_; ++c) a[u] = fmaf(row[c], wr[c], a[u]);
    }
    float4 st; st.x = a[0]; st.y = a[1]; st.z = a[2]; st.w = a[3];
    ((float4*)yp)[og] = st;
  }
}

/* ---------------- K2L: logits via 16x16x32 split-MFMA (proven R13 form) --- */
__global__ __launch_bounds__(256, 4) void k2_logits(const float* __restrict__ w1,
                                                    const float* __restrict__ w2,
                                                    float* __restrict__ ws) {
  __shared__ unsigned short A_s[4][2048];   /* [wave][32 rows][hi32|lo32] 16KB */
  __shared__ float dist_s[4][24];
  const int lane = threadIdx.x & 63;
  const int wv   = __builtin_amdgcn_readfirstlane(threadIdx.x >> 6);
  const int l16 = lane & 15, lg = lane >> 4;
  const int i = blockIdx.x;                 /* 2048 blocks */
  const int xcd = i & 7, j = i >> 3;        /* j 0..255 */
  const int b = 2 * xcd + (j & 1);
  const int grp = j >> 1;                   /* 0..127 : 16-point group */
  const float* Y = ws + WS_Y;

  /* zero A (rows 24..31 and r>=16 slots stay zero forever) */
  {
    uint4 z; z.x = 0; z.y = 0; z.z = 0; z.w = 0;
    uint4* az = (uint4*)&A_s[wv][0];
    az[lane] = z; az[lane + 64] = z; az[lane + 128] = z; az[lane + 192] = z;
  }

  /* W1 B-fragments (hi/lo x 4 o-tiles): lane = o-col l16, elems r=lg*8..+7 */
  bf16x8 w1h[4], w1l[4];
  float w2r[4];
#pragma unroll
  for (int t = 0; t < 4; ++t) {
    const int o = t * 16 + l16;
    w2r[t] = w2[o];
    bf16x8 vh, vl;
#pragma unroll
    for (int jj = 0; jj < 8; ++jj) {
      const int r = lg * 8 + jj;
      float v = (r < 16) ? w1[o * 80 + 64 + r] : 0.f;
      unsigned short h = bf16rne(v);
      float lo = v - __uint_as_float((unsigned int)h << 16);
      vh[jj] = (short)h;
      vl[jj] = (short)bf16rne(lo);
    }
    w1h[t] = vh; w1l[t] = vl;
  }

#pragma unroll 1
  for (int q = 0; q < 4; ++q) {
    const int bn = (b << 11) + (grp << 4) + (wv << 2) + q;        /* uniform */
    const float* dpp = ws + WS_D2 + (size_t)bn * K_;
    if (lane < K_) dist_s[wv][lane] = sqrtf(fmaxf(dpp[lane], 1e-12f));
    /* rbf -> bf16 hi/lo into A rows: 3 (k,r-pair) items per lane */
#pragma unroll
    for (int t = 0; t < 3; ++t) {
      const int f2 = lane + (t << 6);       /* 0..191 = k*8 + r2 */
      const int k = f2 >> 3, r2 = f2 & 7;
      const float d = dist_s[wv][k];
      float d0 = d - (float)(2 * r2    ) * (5.0f / 15.0f);
      float d1 = d - (float)(2 * r2 + 1) * (5.0f / 15.0f);
      float e0 = fminf(fmaxf(__expf(-10.f * d0 * d0), 1e-10f), 1.0f);
      float e1 = fminf(fmaxf(__expf(-10.f * d1 * d1), 1e-10f), 1.0f);
      unsigned short h0 = bf16rne(e0), h1 = bf16rne(e1);
      float lo0 = e0 - __uint_as_float((unsigned int)h0 << 16);
      float lo1 = e1 - __uint_as_float((unsigned int)h1 << 16);
      unsigned short g0 = bf16rne(lo0), g1 = bf16rne(lo1);
      const int slot = r2 >> 2;             /* logical hi slot 0..1 */
      const int us = (2 * r2) & 7;          /* even ushort within slot */
      const int ph = (slot     ^ (k & 7));
      const int pl = ((4|slot) ^ (k & 7));
      *(unsigned int*)&A_s[wv][(k << 6) + (ph << 3) + us] =
          (unsigned int)h0 | ((unsigned int)h1 << 16);
      *(unsigned int*)&A_s[wv][(k << 6) + (pl << 3) + us] =
          (unsigned int)g0 | ((unsigned int)g1 << 16);
    }
    /* ba[o] per o-tile (coalesced) */
    float ba[4];
#pragma unroll
    for (int t = 0; t < 4; ++t) ba[t] = Y[(size_t)bn * 256 + t * 16 + l16];

#pragma unroll
    for (int kt = 0; kt < 2; ++kt) {
      const int row = kt * 16 + l16;
      bf16x8 ah = *(const bf16x8*)&A_s[wv][(row << 6) + (((lg    ) ^ (row & 7)) << 3)];
      bf16x8 al = *(const bf16x8*)&A_s[wv][(row << 6) + (((4 | lg) ^ (row & 7)) << 3)];
      /* neighbor indices for this lane's 4 k's (k = kt*16 + lg*4 + reg) */
      int mk[4];
#pragma unroll
      for (int reg = 0; reg < 4; ++reg) {
        const int k = kt * 16 + (lg << 2) + reg;
        mk[reg] = ((const int*)ws)[WS_IDX + (size_t)bn * K_ + (k < K_ ? k : 0)];
      }
      float sum[4] = {0.f, 0.f, 0.f, 0.f};
#pragma unroll
      for (int t = 0; t < 4; ++t) {
        f32x4 acc;
#pragma unroll
        for (int reg = 0; reg < 4; ++reg) {
          float rv = Y[(size_t)((b << 11) + mk[reg]) * 256 + 64 + t * 16 + l16];
          acc[reg] = ba[t] + rv;            /* C init = ba + rv */
        }
        acc = __builtin_amdgcn_mfma_f32_16x16x32_bf16(ah, w1h[t], acc, 0, 0, 0);
        acc = __builtin_amdgcn_mfma_f32_16x16x32_bf16(al, w1h[t], acc, 0, 0, 0);
        acc = __builtin_amdgcn_mfma_f32_16x16x32_bf16(ah, w1l[t], acc, 0, 0, 0);
#pragma unroll
        for (int reg = 0; reg < 4; ++reg) {
          float a = acc[reg];
          a = fmaxf(a, 0.2f * a);           /* leaky 0.2 */
          sum[reg] = fmaf(a, w2r[t], sum[reg]);
        }
      }
#pragma unroll
      for (int reg = 0; reg < 4; ++reg) {
        float p = sum[reg];
        DPP_ADD(p, 0xB1,  0xf);             /* xor1 */
        DPP_ADD(p, 0x4E,  0xf);             /* xor2 */
        DPP_ADD(p, 0x141, 0xf);             /* xor4 (row_half_mirror) */
        DPP_ADD(p, 0x140, 0xf);             /* xor8 (row_mirror) */
        const int k = kt * 16 + (lg << 2) + reg;
        if (l16 == 0 && k < K_) ws[WS_LOG + (size_t)k * 32768 + bn] = p;
      }
    }
  }
}

/* ---------------- K2S: softmax + att + LDS-privatized W/W2 histograms ----- */
__global__ __launch_bounds__(256) void k2_softmax(float* __restrict__ ws) {
  __shared__ float h[4096];                 /* [0..2047]=W, [2048..4095]=W2 */
  const int i = blockIdx.x;                 /* 128 blocks */
  const int xcd = i & 7, j = i >> 3;        /* j 0..15 */
  const int b = 2 * xcd + (j & 1);
  const int half = j >> 1;                  /* 0..7 */
  const int bn = (b << 11) + (half << 8) + threadIdx.x;

#pragma unroll
  for (int q = 0; q < 16; ++q) h[threadIdx.x + (q << 8)] = 0.f;
  __syncthreads();

  float l[K_];
#pragma unroll
  for (int k = 0; k < K_; ++k) l[k] = ws[WS_LOG + (size_t)k * 32768 + bn];
  float mx = l[0];
#pragma unroll
  for (int k = 1; k < K_; ++k) mx = fmaxf(mx, l[k]);
  float den = 0.f;
#pragma unroll
  for (int k = 0; k < K_; ++k) { l[k] = __expf(l[k] - mx); den += l[k]; }
  const float inv = 1.f / den;
#pragma unroll
  for (int k = 0; k < K_; ++k) l[k] *= inv;

  float4* ap = (float4*)(ws + WS_ATT + (size_t)bn * K_);
#pragma unroll
  for (int q = 0; q < 6; ++q) {
    float4 v; v.x = l[4*q]; v.y = l[4*q+1]; v.z = l[4*q+2]; v.w = l[4*q+3];
    ap[q] = v;
  }
  const int* ip = (const int*)ws + WS_IDX + (size_t)bn * K_;
#pragma unroll
  for (int k = 0; k < K_; ++k) {
    const int mk = ip[k];
    atomicAdd(&h[mk], l[k]);                /* ds_add_f32 */
    atomicAdd(&h[2048 + mk], l[k] * l[k]);
  }
  __syncthreads();
  /* coalesced merge: 2048 bins x 2 arrays / 256 threads */
#pragma unroll
  for (int q = 0; q < 8; ++q) {
    const int m = threadIdx.x + (q << 8);
    atomicAdd(ws + WS_W  + (b << 11) + m, h[m]);
    atomicAdd(ws + WS_W2 + (b << 11) + m, h[2048 + m]);
  }
}

/* ---------------- K2B: BN stats from W/W2 (coalesced sweep) --------------- */
__global__ __launch_bounds__(256) void k2b_stats(float* __restrict__ ws) {
  __shared__ float ls[128];
  const int lane = threadIdx.x & 63;
  const int wv   = __builtin_amdgcn_readfirstlane(threadIdx.x >> 6);
  if (threadIdx.x < 128) ls[threadIdx.x] = 0.f;
  __syncthreads();
  const int i = blockIdx.x;                 /* 128 blocks */
  const int xcd = i & 7, j = i >> 3;
  const int b = 2 * xcd + (j & 1);
  const int half = j >> 1;
  const float* Y = ws + WS_Y;
  float s1 = 0.f, s2 = 0.f;
#pragma unroll 1
  for (int it = 0; it < 64; ++it) {
    const int m = (b << 11) + (half << 8) + (wv << 6) + it;   /* uniform */
    const float w  = ws[WS_W + m];           /* s_load */
    const float w2 = ws[WS_W2 + m];
    const float yv = Y[(size_t)m * 256 + 128 + lane];         /* coalesced */
    s1 = fmaf(w, yv, s1);
    s2 = fmaf(w2, yv * yv, s2);
  }
  atomicAdd(&ls[lane], s1);
  atomicAdd(&ls[64 + lane], s2);
  __syncthreads();
  if (threadIdx.x < 128) atomicAdd(ws + WS_ST + threadIdx.x, ls[threadIdx.x]);
}

/* ---------------- K4: BN finalize (inlined k3) + apply + residual + mean -- */
__global__ __launch_bounds__(256) void k4_out(float* __restrict__ out,
                                              const float* __restrict__ gam,
                                              const float* __restrict__ bet,
                                              const float* __restrict__ ws) {
  __shared__ float tile[32][65];
  const int lane = threadIdx.x & 63;
  const int wv   = __builtin_amdgcn_readfirstlane(threadIdx.x >> 6);
  const int i = blockIdx.x;                 /* 1024 blocks */
  const int xcd = i & 7, j = i >> 3;        /* j 0..127 */
  const int b = 2 * xcd + (j & 1);
  const int j2 = j >> 1;                    /* 0..63 */
  const int n0 = j2 << 5;                   /* 32-point tile */
  const float* Y = ws + WS_Y;

  /* inlined k3: per-lane BN scale/shift from global stats */
  float A, Bb;
  {
    const float s1 = ws[WS_ST + lane], s2 = ws[WS_ST + 64 + lane];
    const float cnt = (float)BNK_;
    const float mean = s1 / cnt;
    const float var = fmaxf(s2 / cnt - mean * mean, 0.f);
    A = gam[lane] / sqrtf(var + 1e-5f);
    Bb = bet[lane] - mean * A;
  }

#pragma unroll 1
  for (int pt = 0; pt < 8; ++pt) {
    const int bn = (b << 11) + n0 + (wv << 3) + pt;           /* uniform */
    const int*   ip = (const int*)ws + WS_IDX + (size_t)bn * K_;   /* s_load */
    const float* ap = ws + WS_ATT + (size_t)bn * K_;               /* s_load */
    float facc = 0.f, racc = 0.f;
#pragma unroll
    for (int k = 0; k < K_; ++k) {
      const int mk = ip[k];
      const float* row = Y + (size_t)((b << 11) + mk) * 256;
      float yv = row[128 + lane];           /* coalesced */
      float rv = row[192 + lane];           /* coalesced */
      float u = ap[k] * yv;
      float v = fmaf(u, A, Bb);
      v = v > 0.f ? v : 0.02f * v;          /* leaky 0.02 */
      facc += v;
      racc += rv;
    }
    tile[(wv << 3) + pt][lane] = (facc + 0.1f * racc) * (1.f / 24.f);
  }
  __syncthreads();
  const int o = threadIdx.x >> 2, q = threadIdx.x & 3;
  float* op = out + ((size_t)(b * 64 + o)) * 2048 + n0 + q * 8;
  float4 v0, v1;
  v0.x = tile[q*8+0][o]; v0.y = tile[q*8+1][o]; v0.z = tile[q*8+2][o]; v0.w = tile[q*8+3][o];
  v1.x = tile[q*8+4][o]; v1.y = tile[q*8+5][o]; v1.z = tile[q*8+6][o]; v1.w = tile[q*8+7][o];
  ((float4*)op)[0] = v0;
  ((float4*)op)[1] = v1;
}

extern "C" void kernel_launch(void* const* d_in, const int* in_sizes, int n_in,
                              void* d_out, int out_size, void* d_ws, size_t ws_size,
                              hipStream_t stream) {
  (void)in_sizes; (void)n_in; (void)out_size; (void)ws_size;
  const float* x    = (const float*)d_in[0];
  /* d_in[1] = idx_base (unused by reference) */
  const float* w1   = (const float*)d_in[2];
  const float* w2   = (const float*)d_in[3];
  const float* updw = (const float*)d_in[4];
  const float* bng  = (const float*)d_in[5];
  const float* bnb  = (const float*)d_in[6];
  const float* resw = (const float*)d_in[7];
  float* out = (float*)d_out;
  float* ws  = (float*)d_ws;

  k0_prep  <<<dim3(128),  dim3(256), 0, stream>>>(x, ws);
  k1a_mfma <<<dim3(2048), dim3(256), 0, stream>>>(ws);
  k1b_sel  <<<dim3(512),  dim3(256), 0, stream>>>(ws);
  kY       <<<dim3(1024), dim3(256), 0, stream>>>(w1, updw, resw, ws);
  k2_logits<<<dim3(2048), dim3(256), 0, stream>>>(w1, w2, ws);
  k2_softmax<<<dim3(128), dim3(256), 0, stream>>>(ws);
  k2b_stats<<<dim3(128),  dim3(256), 0, stream>>>(ws);
  k4_out   <<<dim3(1024), dim3(256), 0, stream>>>(out, bng, bnb, ws);
}